// Round 1
// baseline (499.192 us; speedup 1.0000x reference)
//
#include <hip/hip_runtime.h>

#define NN 50000
#define NP 25000
#define NE 800000
#define DD 64
#define NL 4

// ---- CSR build ----------------------------------------------------------

__global__ void count_edges_k(const int* __restrict__ dst, int* __restrict__ cnt, int E) {
    int e = blockIdx.x * 256 + threadIdx.x;
    if (e < E) atomicAdd(&cnt[dst[e]], 1);
}

__global__ void scan_local_k(const int* __restrict__ cnt, int* __restrict__ rowptr,
                             int* __restrict__ bsum, int n) {
    __shared__ int tmp[1024];
    int t = threadIdx.x;
    int i = blockIdx.x * 1024 + t;
    int v = (i < n) ? cnt[i] : 0;
    tmp[t] = v;
    __syncthreads();
    for (int off = 1; off < 1024; off <<= 1) {
        int a = (t >= off) ? tmp[t - off] : 0;
        __syncthreads();
        tmp[t] += a;
        __syncthreads();
    }
    if (i < n) rowptr[i] = tmp[t] - v;      // block-local exclusive scan
    if (t == 1023) bsum[blockIdx.x] = tmp[1023];
}

__global__ void scan_sums_k(int* bsum, int nb, int* rowptr, int n) {
    if (threadIdx.x == 0 && blockIdx.x == 0) {
        int run = 0;
        for (int b = 0; b < nb; ++b) { int s = bsum[b]; bsum[b] = run; run += s; }
        rowptr[n] = run;
    }
}

__global__ void finalize_k(int* __restrict__ rowptr, const int* __restrict__ bsum,
                           const int* __restrict__ cnt, float* __restrict__ dinv,
                           int* __restrict__ cursor, int n) {
    int i = blockIdx.x * 1024 + threadIdx.x;
    if (i < n) {
        rowptr[i] += bsum[blockIdx.x];
        dinv[i] = rsqrtf((float)(cnt[i] + 1));   // +1 self loop; deg >= 1 always
        cursor[i] = 0;
    }
}

__global__ void fill_csr_k(const int* __restrict__ src, const int* __restrict__ dst,
                           const int* __restrict__ rowptr, int* __restrict__ cursor,
                           const float* __restrict__ dinv, int* __restrict__ csr_src,
                           float* __restrict__ csr_w, int E) {
    int e = blockIdx.x * 256 + threadIdx.x;
    if (e >= E) return;
    int s = src[e], d = dst[e];
    int p = rowptr[d] + atomicAdd(&cursor[d], 1);
    csr_src[p] = s;
    csr_w[p] = dinv[s] * dinv[d];
}

// ---- unpool scatter -----------------------------------------------------

__global__ void scatter_x_k(const float4* __restrict__ x4, const int* __restrict__ idx,
                            float4* __restrict__ cur4) {
    int i = blockIdx.x * 256 + threadIdx.x;   // NP*16 float4s
    if (i >= NP * 16) return;
    int row = i >> 4, q = i & 15;
    cur4[(size_t)idx[row] * 16 + q] = x4[i];
}

// ---- GEMM: out[50000x64] = in[50000x64] @ W[64x64] ----------------------

__global__ void gemm64_k(const float* __restrict__ in, const float* __restrict__ W,
                         float* __restrict__ out) {
    __shared__ float sW[64][64];     // 16 KB
    __shared__ float srow[16][64];   // 4 KB
    int t = threadIdx.x;             // 256 threads
    const float4* W4 = (const float4*)W;
    float4* sW4 = (float4*)sW;
#pragma unroll
    for (int j = 0; j < 4; ++j) sW4[t + 256 * j] = W4[t + 256 * j];
    int r0 = blockIdx.x * 16;
    const float4* in4 = (const float4*)(in + (size_t)r0 * 64);
    ((float4*)srow)[t] = in4[t];
    __syncthreads();
    int r = t >> 4;            // 0..15
    int c4 = (t & 15) * 4;     // 0,4,...,60
    float ax = 0.f, ay = 0.f, az = 0.f, aw = 0.f;
#pragma unroll
    for (int k = 0; k < 64; ++k) {
        float a = srow[r][k];
        float4 w = *(const float4*)&sW[k][c4];
        ax += a * w.x; ay += a * w.y; az += a * w.z; aw += a * w.w;
    }
    float4 o; o.x = ax; o.y = ay; o.z = az; o.w = aw;
    *(float4*)&out[(size_t)(r0 + r) * 64 + c4] = o;
}

// ---- fused: aggregate + bias + LayerNorm + LeakyReLU + h accumulate -----

__global__ void agg_ln_k(const float* __restrict__ xw, const int* __restrict__ rowptr,
                         const int* __restrict__ csr_src, const float* __restrict__ csr_w,
                         const float* __restrict__ dinv, const float* __restrict__ bias,
                         const float* __restrict__ gamma, const float* __restrict__ beta,
                         float* __restrict__ cur, float* __restrict__ h, int first) {
    int lane = threadIdx.x & 63;
    int v = blockIdx.x * 4 + (threadIdx.x >> 6);   // 4 waves/block, 1 node/wave
    float dv = dinv[v];
    float acc = dv * dv * xw[(size_t)v * 64 + lane];   // self loop
    int jb = rowptr[v], je = rowptr[v + 1];
    for (int j = jb; j < je; ++j) {
        int u = csr_src[j];
        acc += csr_w[j] * xw[(size_t)u * 64 + lane];
    }
    acc += bias[lane];
    // LayerNorm across the 64 lanes (D=64)
    float s = acc;
#pragma unroll
    for (int o = 32; o >= 1; o >>= 1) s += __shfl_xor(s, o);
    float mu = s * (1.0f / 64.0f);
    float xc = acc - mu;
    float q = xc * xc;
#pragma unroll
    for (int o = 32; o >= 1; o >>= 1) q += __shfl_xor(q, o);
    float rs = rsqrtf(q * (1.0f / 64.0f) + 1e-5f);
    float y = xc * rs * gamma[lane] + beta[lane];
    float act = (y > 0.f) ? y : 0.01f * y;
    float hv = act * 0.5f;
    size_t o64 = (size_t)v * 64 + lane;
    if (!first) hv += h[o64];
    h[o64] = hv;
    cur[o64] = act;
}

// ---- launch -------------------------------------------------------------

extern "C" void kernel_launch(void* const* d_in, const int* in_sizes, int n_in,
                              void* d_out, int out_size, void* d_ws, size_t ws_size,
                              hipStream_t stream) {
    const float* x      = (const float*)d_in[0];
    const int*   ei     = (const int*)d_in[1];
    const int*   src    = ei;
    const int*   dst    = ei + NE;
    const int*   idx    = (const int*)d_in[2];
    const float* Ws     = (const float*)d_in[3];
    const float* bs     = (const float*)d_in[4];
    const float* gammas = (const float*)d_in[5];
    const float* betas  = (const float*)d_in[6];
    float* out = (float*)d_out;

    char* w = (char*)d_ws;
    auto alloc = [&](size_t bytes) -> char* {
        char* p = w;
        w += (bytes + 255) & ~(size_t)255;
        return p;
    };
    float* cur     = (float*)alloc((size_t)NN * 64 * 4);
    float* xw      = (float*)alloc((size_t)NN * 64 * 4);
    int*   cnt     = (int*)alloc((size_t)NN * 4);
    int*   rowptr  = (int*)alloc((size_t)(NN + 1) * 4);
    int*   cursor  = (int*)alloc((size_t)NN * 4);
    float* dinv    = (float*)alloc((size_t)NN * 4);
    int*   bsum    = (int*)alloc(64 * 4);
    int*   csr_src = (int*)alloc((size_t)NE * 4);
    float* csr_w   = (float*)alloc((size_t)NE * 4);

    hipMemsetAsync(cnt, 0, (size_t)NN * 4, stream);
    hipMemsetAsync(cur, 0, (size_t)NN * 64 * 4, stream);

    count_edges_k<<<(NE + 255) / 256, 256, 0, stream>>>(dst, cnt, NE);
    int nb = (NN + 1023) / 1024;   // 49
    scan_local_k<<<nb, 1024, 0, stream>>>(cnt, rowptr, bsum, NN);
    scan_sums_k<<<1, 64, 0, stream>>>(bsum, nb, rowptr, NN);
    finalize_k<<<nb, 1024, 0, stream>>>(rowptr, bsum, cnt, dinv, cursor, NN);
    fill_csr_k<<<(NE + 255) / 256, 256, 0, stream>>>(src, dst, rowptr, cursor, dinv,
                                                     csr_src, csr_w, NE);
    scatter_x_k<<<(NP * 16 + 255) / 256, 256, 0, stream>>>((const float4*)x, idx, (float4*)cur);

    for (int l = 0; l < NL; ++l) {
        gemm64_k<<<NN / 16, 256, 0, stream>>>(cur, Ws + l * 64 * 64, xw);
        agg_ln_k<<<NN / 4, 256, 0, stream>>>(xw, rowptr, csr_src, csr_w, dinv,
                                             bs + l * 64, gammas + l * 64, betas + l * 64,
                                             cur, out, l == 0 ? 1 : 0);
    }
}

// Round 2
// 328.963 us; speedup vs baseline: 1.5175x; 1.5175x over previous
//
#include <hip/hip_runtime.h>

#define NN 50000
#define NP 25000
#define NE 800000
#define DD 64
#define NL 4

// ---- CSR build ----------------------------------------------------------

__global__ void count_edges_k(const int* __restrict__ dst, int* __restrict__ cnt, int E) {
    int e = blockIdx.x * 256 + threadIdx.x;
    if (e < E) atomicAdd(&cnt[dst[e]], 1);
}

__global__ void scan_local_k(const int* __restrict__ cnt, int* __restrict__ rowptr,
                             int* __restrict__ bsum, int n) {
    __shared__ int tmp[1024];
    int t = threadIdx.x;
    int i = blockIdx.x * 1024 + t;
    int v = (i < n) ? cnt[i] : 0;
    tmp[t] = v;
    __syncthreads();
    for (int off = 1; off < 1024; off <<= 1) {
        int a = (t >= off) ? tmp[t - off] : 0;
        __syncthreads();
        tmp[t] += a;
        __syncthreads();
    }
    if (i < n) rowptr[i] = tmp[t] - v;      // block-local exclusive scan
    if (t == 1023) bsum[blockIdx.x] = tmp[1023];
}

__global__ void scan_sums_k(int* bsum, int nb, int* rowptr, int n) {
    if (threadIdx.x == 0 && blockIdx.x == 0) {
        int run = 0;
        for (int b = 0; b < nb; ++b) { int s = bsum[b]; bsum[b] = run; run += s; }
        rowptr[n] = run;
    }
}

__global__ void finalize_k(int* __restrict__ rowptr, const int* __restrict__ bsum,
                           const int* __restrict__ cnt, float* __restrict__ dinv,
                           int* __restrict__ cursor, int n) {
    int i = blockIdx.x * 1024 + threadIdx.x;
    if (i < n) {
        rowptr[i] += bsum[blockIdx.x];
        dinv[i] = rsqrtf((float)(cnt[i] + 1));   // +1 self loop; deg >= 1 always
        cursor[i] = 0;
    }
}

__global__ void fill_csr_k(const int* __restrict__ src, const int* __restrict__ dst,
                           const int* __restrict__ rowptr, int* __restrict__ cursor,
                           const float* __restrict__ dinv, int2* __restrict__ csr_sw, int E) {
    int e = blockIdx.x * 256 + threadIdx.x;
    if (e >= E) return;
    int s = src[e], d = dst[e];
    int p = rowptr[d] + atomicAdd(&cursor[d], 1);
    csr_sw[p] = make_int2(s, __float_as_int(dinv[s] * dinv[d]));
}

// ---- unpool scatter -----------------------------------------------------

__global__ void scatter_x_k(const float4* __restrict__ x4, const int* __restrict__ idx,
                            float4* __restrict__ cur4) {
    int i = blockIdx.x * 256 + threadIdx.x;   // NP*16 float4s
    if (i >= NP * 16) return;
    int row = i >> 4, q = i & 15;
    cur4[(size_t)idx[row] * 16 + q] = x4[i];
}

// ---- GEMM: out[50000x64] = in[50000x64] @ W[64x64] ----------------------

__global__ void gemm64_k(const float* __restrict__ in, const float* __restrict__ W,
                         float* __restrict__ out) {
    __shared__ float sW[64][64];     // 16 KB
    __shared__ float srow[16][64];   // 4 KB
    int t = threadIdx.x;             // 256 threads
    const float4* W4 = (const float4*)W;
    float4* sW4 = (float4*)sW;
#pragma unroll
    for (int j = 0; j < 4; ++j) sW4[t + 256 * j] = W4[t + 256 * j];
    int r0 = blockIdx.x * 16;
    const float4* in4 = (const float4*)(in + (size_t)r0 * 64);
    ((float4*)srow)[t] = in4[t];
    __syncthreads();
    int r = t >> 4;            // 0..15
    int c4 = (t & 15) * 4;     // 0,4,...,60
    float ax = 0.f, ay = 0.f, az = 0.f, aw = 0.f;
#pragma unroll
    for (int k = 0; k < 64; ++k) {
        float a = srow[r][k];
        float4 w = *(const float4*)&sW[k][c4];
        ax += a * w.x; ay += a * w.y; az += a * w.z; aw += a * w.w;
    }
    float4 o; o.x = ax; o.y = ay; o.z = az; o.w = aw;
    *(float4*)&out[(size_t)(r0 + r) * 64 + c4] = o;
}

// ---- fused: aggregate + bias + LayerNorm + LeakyReLU + h accumulate -----
// 1 node per wave; wave split into 4 groups of 16 lanes. Group g handles
// edge slot jb+g+4k; each lane loads float4 (16 lanes cover the 64-f row).
// 2x unrolled -> 8 row-gathers in flight per wave.

__global__ void agg_ln_k(const float4* __restrict__ xw4, const int* __restrict__ rowptr,
                         const int2* __restrict__ csr_sw,
                         const float* __restrict__ dinv, const float4* __restrict__ bias4,
                         const float4* __restrict__ gamma4, const float4* __restrict__ beta4,
                         float4* __restrict__ cur4, float4* __restrict__ h4, int first) {
    int tid = threadIdx.x;
    int lane = tid & 63;
    int g = lane >> 4;          // edge-slot group 0..3
    int fl = lane & 15;         // feature quad 0..15
    int v = blockIdx.x * 4 + (tid >> 6);
    float dv = dinv[v];
    int jb = rowptr[v], je = rowptr[v + 1];
    float4 acc = make_float4(0.f, 0.f, 0.f, 0.f);
    if (g == 0) {                               // self loop, added once
        float4 r = xw4[(size_t)v * 16 + fl];
        float s = dv * dv;
        acc.x = s * r.x; acc.y = s * r.y; acc.z = s * r.z; acc.w = s * r.w;
    }
    for (int j = jb + g; j < je; j += 8) {
        int j2 = j + 4;
        int2 sw1 = csr_sw[j];
        int2 sw2 = (j2 < je) ? csr_sw[j2] : make_int2(sw1.x, 0);
        float4 r1 = xw4[(size_t)sw1.x * 16 + fl];
        float4 r2 = xw4[(size_t)sw2.x * 16 + fl];
        float w1 = __int_as_float(sw1.y);
        float w2 = __int_as_float(sw2.y);
        acc.x += w1 * r1.x + w2 * r2.x;
        acc.y += w1 * r1.y + w2 * r2.y;
        acc.z += w1 * r1.z + w2 * r2.z;
        acc.w += w1 * r1.w + w2 * r2.w;
    }
    // combine the 4 edge-slot groups (feature layout identical across groups)
#pragma unroll
    for (int o = 16; o <= 32; o <<= 1) {
        acc.x += __shfl_xor(acc.x, o);
        acc.y += __shfl_xor(acc.y, o);
        acc.z += __shfl_xor(acc.z, o);
        acc.w += __shfl_xor(acc.w, o);
    }
    float4 b = bias4[fl];
    acc.x += b.x; acc.y += b.y; acc.z += b.z; acc.w += b.w;
    // LayerNorm over 64 features (= 16 lanes x 4 components; groups identical)
    float s = acc.x + acc.y + acc.z + acc.w;
#pragma unroll
    for (int o = 1; o <= 8; o <<= 1) s += __shfl_xor(s, o);
    float mu = s * (1.0f / 64.0f);
    float4 xc = make_float4(acc.x - mu, acc.y - mu, acc.z - mu, acc.w - mu);
    float q = xc.x * xc.x + xc.y * xc.y + xc.z * xc.z + xc.w * xc.w;
#pragma unroll
    for (int o = 1; o <= 8; o <<= 1) q += __shfl_xor(q, o);
    float rs = rsqrtf(q * (1.0f / 64.0f) + 1e-5f);
    float4 gm = gamma4[fl], bt = beta4[fl];
    float4 y = make_float4(xc.x * rs * gm.x + bt.x, xc.y * rs * gm.y + bt.y,
                           xc.z * rs * gm.z + bt.z, xc.w * rs * gm.w + bt.w);
    float4 act = make_float4(y.x > 0.f ? y.x : 0.01f * y.x,
                             y.y > 0.f ? y.y : 0.01f * y.y,
                             y.z > 0.f ? y.z : 0.01f * y.z,
                             y.w > 0.f ? y.w : 0.01f * y.w);
    if (g == 0) {                       // 16 lanes write the full 256B row
        size_t o16 = (size_t)v * 16 + fl;
        float4 hv = make_float4(act.x * 0.5f, act.y * 0.5f, act.z * 0.5f, act.w * 0.5f);
        if (!first) {
            float4 hp = h4[o16];
            hv.x += hp.x; hv.y += hp.y; hv.z += hp.z; hv.w += hp.w;
        }
        h4[o16] = hv;
        cur4[o16] = act;
    }
}

// ---- launch -------------------------------------------------------------

extern "C" void kernel_launch(void* const* d_in, const int* in_sizes, int n_in,
                              void* d_out, int out_size, void* d_ws, size_t ws_size,
                              hipStream_t stream) {
    const float* x      = (const float*)d_in[0];
    const int*   ei     = (const int*)d_in[1];
    const int*   src    = ei;
    const int*   dst    = ei + NE;
    const int*   idx    = (const int*)d_in[2];
    const float* Ws     = (const float*)d_in[3];
    const float* bs     = (const float*)d_in[4];
    const float* gammas = (const float*)d_in[5];
    const float* betas  = (const float*)d_in[6];
    float* out = (float*)d_out;

    char* w = (char*)d_ws;
    auto alloc = [&](size_t bytes) -> char* {
        char* p = w;
        w += (bytes + 255) & ~(size_t)255;
        return p;
    };
    float* cur     = (float*)alloc((size_t)NN * 64 * 4);
    float* xw      = (float*)alloc((size_t)NN * 64 * 4);
    int*   cnt     = (int*)alloc((size_t)NN * 4);
    int*   rowptr  = (int*)alloc((size_t)(NN + 1) * 4);
    int*   cursor  = (int*)alloc((size_t)NN * 4);
    float* dinv    = (float*)alloc((size_t)NN * 4);
    int*   bsum    = (int*)alloc(64 * 4);
    int2*  csr_sw  = (int2*)alloc((size_t)NE * 8);

    hipMemsetAsync(cnt, 0, (size_t)NN * 4, stream);
    hipMemsetAsync(cur, 0, (size_t)NN * 64 * 4, stream);

    count_edges_k<<<(NE + 255) / 256, 256, 0, stream>>>(dst, cnt, NE);
    int nb = (NN + 1023) / 1024;   // 49
    scan_local_k<<<nb, 1024, 0, stream>>>(cnt, rowptr, bsum, NN);
    scan_sums_k<<<1, 64, 0, stream>>>(bsum, nb, rowptr, NN);
    finalize_k<<<nb, 1024, 0, stream>>>(rowptr, bsum, cnt, dinv, cursor, NN);
    fill_csr_k<<<(NE + 255) / 256, 256, 0, stream>>>(src, dst, rowptr, cursor, dinv,
                                                     csr_sw, NE);
    scatter_x_k<<<(NP * 16 + 255) / 256, 256, 0, stream>>>((const float4*)x, idx, (float4*)cur);

    for (int l = 0; l < NL; ++l) {
        gemm64_k<<<NN / 16, 256, 0, stream>>>(cur, Ws + l * 64 * 64, xw);
        agg_ln_k<<<NN / 4, 256, 0, stream>>>((const float4*)xw, rowptr, csr_sw, dinv,
                                             (const float4*)(bs + l * 64),
                                             (const float4*)(gammas + l * 64),
                                             (const float4*)(betas + l * 64),
                                             (float4*)cur, (float4*)out, l == 0 ? 1 : 0);
    }
}

// Round 3
// 289.427 us; speedup vs baseline: 1.7248x; 1.1366x over previous
//
#include <hip/hip_runtime.h>

#define NN 50000
#define NP 25000
#define NE 800000
#define DD 64
#define NL 4

// ---- helpers ------------------------------------------------------------

__device__ __forceinline__ ushort f2bf(float f) {
    unsigned u = __float_as_uint(f);
    unsigned r = (u + 0x7fffu + ((u >> 16) & 1u)) >> 16;   // RNE
    return (ushort)r;
}

__device__ __forceinline__ float4 ld_bf16x4(const uint2* p) {
    uint2 q = *p;
    float4 r;
    r.x = __uint_as_float((q.x & 0xffffu) << 16);
    r.y = __uint_as_float(q.x & 0xffff0000u);
    r.z = __uint_as_float((q.y & 0xffffu) << 16);
    r.w = __uint_as_float(q.y & 0xffff0000u);
    return r;
}

// ---- CSR build ----------------------------------------------------------

__global__ void count_edges_k(const int* __restrict__ dst, int* __restrict__ cnt, int E) {
    int e = blockIdx.x * 256 + threadIdx.x;
    if (e < E) atomicAdd(&cnt[dst[e]], 1);
}

__global__ void scan_local_k(const int* __restrict__ cnt, int* __restrict__ rowptr,
                             int* __restrict__ bsum, int n) {
    __shared__ int tmp[1024];
    int t = threadIdx.x;
    int i = blockIdx.x * 1024 + t;
    int v = (i < n) ? cnt[i] : 0;
    tmp[t] = v;
    __syncthreads();
    for (int off = 1; off < 1024; off <<= 1) {
        int a = (t >= off) ? tmp[t - off] : 0;
        __syncthreads();
        tmp[t] += a;
        __syncthreads();
    }
    if (i < n) rowptr[i] = tmp[t] - v;      // block-local exclusive scan
    if (t == 1023) bsum[blockIdx.x] = tmp[1023];
}

__global__ void scan_sums_k(int* bsum, int nb, int* rowptr, int n) {
    if (threadIdx.x == 0 && blockIdx.x == 0) {
        int run = 0;
        for (int b = 0; b < nb; ++b) { int s = bsum[b]; bsum[b] = run; run += s; }
        rowptr[n] = run;
    }
}

__global__ void finalize_k(int* __restrict__ rowptr, const int* __restrict__ bsum,
                           const int* __restrict__ cnt, float* __restrict__ dinv,
                           int* __restrict__ cursor, int n) {
    int i = blockIdx.x * 1024 + threadIdx.x;
    if (i < n) {
        rowptr[i] += bsum[blockIdx.x];
        dinv[i] = rsqrtf((float)(cnt[i] + 1));   // +1 self loop; deg >= 1 always
        cursor[i] = 0;
    }
}

__global__ void fill_csr_k(const int* __restrict__ src, const int* __restrict__ dst,
                           const int* __restrict__ rowptr, int* __restrict__ cursor,
                           const float* __restrict__ dinv, int2* __restrict__ csr_sw, int E) {
    int e = blockIdx.x * 256 + threadIdx.x;
    if (e >= E) return;
    int s = src[e], d = dst[e];
    int p = rowptr[d] + atomicAdd(&cursor[d], 1);
    csr_sw[p] = make_int2(s, __float_as_int(dinv[s] * dinv[d]));
}

// ---- unpool scatter -----------------------------------------------------

__global__ void scatter_x_k(const float4* __restrict__ x4, const int* __restrict__ idx,
                            float4* __restrict__ cur4) {
    int i = blockIdx.x * 256 + threadIdx.x;   // NP*16 float4s
    if (i >= NP * 16) return;
    int row = i >> 4, q = i & 15;
    cur4[(size_t)idx[row] * 16 + q] = x4[i];
}

// ---- GEMM: xw_bf16[50000x64] = in[50000x64] @ W[64x64] ------------------

__global__ void gemm64_k(const float* __restrict__ in, const float* __restrict__ W,
                         ushort* __restrict__ out) {
    __shared__ float sW[64][64];     // 16 KB
    __shared__ float srow[16][64];   // 4 KB
    int t = threadIdx.x;             // 256 threads
    const float4* W4 = (const float4*)W;
    float4* sW4 = (float4*)sW;
#pragma unroll
    for (int j = 0; j < 4; ++j) sW4[t + 256 * j] = W4[t + 256 * j];
    int r0 = blockIdx.x * 16;
    const float4* in4 = (const float4*)(in + (size_t)r0 * 64);
    ((float4*)srow)[t] = in4[t];
    __syncthreads();
    int r = t >> 4;            // 0..15
    int c4 = (t & 15) * 4;     // 0,4,...,60
    float ax = 0.f, ay = 0.f, az = 0.f, aw = 0.f;
#pragma unroll
    for (int k = 0; k < 64; ++k) {
        float a = srow[r][k];
        float4 w = *(const float4*)&sW[k][c4];
        ax += a * w.x; ay += a * w.y; az += a * w.z; aw += a * w.w;
    }
    ushort4 o;
    o.x = f2bf(ax); o.y = f2bf(ay); o.z = f2bf(az); o.w = f2bf(aw);
    *(ushort4*)&out[(size_t)(r0 + r) * 64 + c4] = o;
}

// ---- fused: aggregate(bf16 gather) + bias + LN + LeakyReLU + h ----------
// 1 node/wave; 4 groups of 16 lanes; group g handles slots jb+g+4k, 4-way
// unrolled -> 16 edges in flight per wave. Lane fl loads uint2 = 4 bf16
// features; 16 lanes cover the 128B row.

__global__ void agg_ln_k(const uint2* __restrict__ xw2, const int* __restrict__ rowptr,
                         const int2* __restrict__ csr_sw,
                         const float* __restrict__ dinv, const float4* __restrict__ bias4,
                         const float4* __restrict__ gamma4, const float4* __restrict__ beta4,
                         float4* __restrict__ cur4, float4* __restrict__ h4, int first) {
    int tid = threadIdx.x;
    int lane = tid & 63;
    int g = lane >> 4;          // edge-slot group 0..3
    int fl = lane & 15;         // feature quad 0..15
    int v = blockIdx.x * 4 + (tid >> 6);
    float dv = dinv[v];
    int jb = rowptr[v], je = rowptr[v + 1];
    float4 acc = make_float4(0.f, 0.f, 0.f, 0.f);
    if (g == 0) {                               // self loop, added once
        float4 r = ld_bf16x4(xw2 + (size_t)v * 16 + fl);
        float s = dv * dv;
        acc.x = s * r.x; acc.y = s * r.y; acc.z = s * r.z; acc.w = s * r.w;
    }
    for (int j = jb + g; j < je; j += 16) {
        int ja = j + 4, jb2 = j + 8, jc = j + 12;
        int2 s0 = csr_sw[j];
        int2 s1 = csr_sw[min(ja, je - 1)];
        int2 s2 = csr_sw[min(jb2, je - 1)];
        int2 s3 = csr_sw[min(jc, je - 1)];
        float w0 = __int_as_float(s0.y);
        float w1 = (ja  < je) ? __int_as_float(s1.y) : 0.f;
        float w2 = (jb2 < je) ? __int_as_float(s2.y) : 0.f;
        float w3 = (jc  < je) ? __int_as_float(s3.y) : 0.f;
        float4 r0 = ld_bf16x4(xw2 + (size_t)s0.x * 16 + fl);
        float4 r1 = ld_bf16x4(xw2 + (size_t)s1.x * 16 + fl);
        float4 r2 = ld_bf16x4(xw2 + (size_t)s2.x * 16 + fl);
        float4 r3 = ld_bf16x4(xw2 + (size_t)s3.x * 16 + fl);
        acc.x += w0 * r0.x + w1 * r1.x + w2 * r2.x + w3 * r3.x;
        acc.y += w0 * r0.y + w1 * r1.y + w2 * r2.y + w3 * r3.y;
        acc.z += w0 * r0.z + w1 * r1.z + w2 * r2.z + w3 * r3.z;
        acc.w += w0 * r0.w + w1 * r1.w + w2 * r2.w + w3 * r3.w;
    }
    // combine the 4 edge-slot groups (feature layout identical across groups)
#pragma unroll
    for (int o = 16; o <= 32; o <<= 1) {
        acc.x += __shfl_xor(acc.x, o);
        acc.y += __shfl_xor(acc.y, o);
        acc.z += __shfl_xor(acc.z, o);
        acc.w += __shfl_xor(acc.w, o);
    }
    float4 b = bias4[fl];
    acc.x += b.x; acc.y += b.y; acc.z += b.z; acc.w += b.w;
    // LayerNorm over 64 features (= 16 lanes x 4 comps; groups hold copies)
    float s = acc.x + acc.y + acc.z + acc.w;
#pragma unroll
    for (int o = 1; o <= 8; o <<= 1) s += __shfl_xor(s, o);
    float mu = s * (1.0f / 64.0f);
    float4 xc = make_float4(acc.x - mu, acc.y - mu, acc.z - mu, acc.w - mu);
    float q = xc.x * xc.x + xc.y * xc.y + xc.z * xc.z + xc.w * xc.w;
#pragma unroll
    for (int o = 1; o <= 8; o <<= 1) q += __shfl_xor(q, o);
    float rs = rsqrtf(q * (1.0f / 64.0f) + 1e-5f);
    float4 gm = gamma4[fl], bt = beta4[fl];
    float4 y = make_float4(xc.x * rs * gm.x + bt.x, xc.y * rs * gm.y + bt.y,
                           xc.z * rs * gm.z + bt.z, xc.w * rs * gm.w + bt.w);
    float4 act = make_float4(y.x > 0.f ? y.x : 0.01f * y.x,
                             y.y > 0.f ? y.y : 0.01f * y.y,
                             y.z > 0.f ? y.z : 0.01f * y.z,
                             y.w > 0.f ? y.w : 0.01f * y.w);
    if (g == 0) {                       // 16 lanes write the full 256B row
        size_t o16 = (size_t)v * 16 + fl;
        float4 hv = make_float4(act.x * 0.5f, act.y * 0.5f, act.z * 0.5f, act.w * 0.5f);
        if (!first) {
            float4 hp = h4[o16];
            hv.x += hp.x; hv.y += hp.y; hv.z += hp.z; hv.w += hp.w;
        }
        h4[o16] = hv;
        cur4[o16] = act;
    }
}

// ---- launch -------------------------------------------------------------

extern "C" void kernel_launch(void* const* d_in, const int* in_sizes, int n_in,
                              void* d_out, int out_size, void* d_ws, size_t ws_size,
                              hipStream_t stream) {
    const float* x      = (const float*)d_in[0];
    const int*   ei     = (const int*)d_in[1];
    const int*   src    = ei;
    const int*   dst    = ei + NE;
    const int*   idx    = (const int*)d_in[2];
    const float* Ws     = (const float*)d_in[3];
    const float* bs     = (const float*)d_in[4];
    const float* gammas = (const float*)d_in[5];
    const float* betas  = (const float*)d_in[6];
    float* out = (float*)d_out;

    char* w = (char*)d_ws;
    auto alloc = [&](size_t bytes) -> char* {
        char* p = w;
        w += (bytes + 255) & ~(size_t)255;
        return p;
    };
    float*  cur    = (float*)alloc((size_t)NN * 64 * 4);
    ushort* xw     = (ushort*)alloc((size_t)NN * 64 * 2);
    int*    cnt    = (int*)alloc((size_t)NN * 4);
    int*    rowptr = (int*)alloc((size_t)(NN + 1) * 4);
    int*    cursor = (int*)alloc((size_t)NN * 4);
    float*  dinv   = (float*)alloc((size_t)NN * 4);
    int*    bsum   = (int*)alloc(64 * 4);
    int2*   csr_sw = (int2*)alloc((size_t)NE * 8);

    hipMemsetAsync(cnt, 0, (size_t)NN * 4, stream);
    hipMemsetAsync(cur, 0, (size_t)NN * 64 * 4, stream);

    count_edges_k<<<(NE + 255) / 256, 256, 0, stream>>>(dst, cnt, NE);
    int nb = (NN + 1023) / 1024;   // 49
    scan_local_k<<<nb, 1024, 0, stream>>>(cnt, rowptr, bsum, NN);
    scan_sums_k<<<1, 64, 0, stream>>>(bsum, nb, rowptr, NN);
    finalize_k<<<nb, 1024, 0, stream>>>(rowptr, bsum, cnt, dinv, cursor, NN);
    fill_csr_k<<<(NE + 255) / 256, 256, 0, stream>>>(src, dst, rowptr, cursor, dinv,
                                                     csr_sw, NE);
    scatter_x_k<<<(NP * 16 + 255) / 256, 256, 0, stream>>>((const float4*)x, idx, (float4*)cur);

    for (int l = 0; l < NL; ++l) {
        gemm64_k<<<NN / 16, 256, 0, stream>>>(cur, Ws + l * 64 * 64, xw);
        agg_ln_k<<<NN / 4, 256, 0, stream>>>((const uint2*)xw, rowptr, csr_sw, dinv,
                                             (const float4*)(bs + l * 64),
                                             (const float4*)(gammas + l * 64),
                                             (const float4*)(betas + l * 64),
                                             (float4*)cur, (float4*)out, l == 0 ? 1 : 0);
    }
}